// Round 1
// baseline (100.768 us; speedup 1.0000x reference)
//
#include <hip/hip_runtime.h>

#define BATCH 2048
#define IC 64
#define OC 64
#define NSH 45
#define NSH_PAD 48
#define BT 16                    // batch rows per block
#define CG 8                     // coefficients per block
#define NCG 6                    // ceil(45/8)
#define NBT (BATCH / BT)         // 128
#define XTOT ((size_t)BATCH * IC * NSH)   // 5,898,240 floats
#define WF_ELEMS (NSH_PAD * IC * OC)      // 196,608 floats
#define PI_F 3.14159265358979323846f

// LDS layout: xs[c][bg][i][bl]  (c<8, bg<2, i<64, bl<8)
// strides chosen for bank-conflict-free ds_read_b128:
//   bank(first dword) = (4*c + 16*bg) mod 32 -> 8 disjoint 4-bank spans
#define C_STRIDE 1060            // floats (= 2*528 + 4)
#define BG_STRIDE 528            // floats (= 64*8 + 16)

typedef float f4u __attribute__((ext_vector_type(4), aligned(4)));

// ---------------- weight fold: wf[c][i][o] = weights[o][i][ls[c]/2] * sqrt(pi/(2l+1))
__global__ __launch_bounds__(256) void fold_kernel(const float* __restrict__ w,
                                                   const int* __restrict__ ls,
                                                   float* __restrict__ wf) {
    int idx = blockIdx.x * 256 + threadIdx.x;   // [0, 48*64*64)
    int o = idx & 63;
    int i = (idx >> 6) & 63;
    int c = idx >> 12;
    float v = 0.0f;
    if (c < NSH) {
        int l = ls[c];
        float sc = sqrtf(PI_F / (2.0f * (float)l + 1.0f));
        v = w[(o * IC + i) * 5 + (l >> 1)] * sc;
    }
    wf[idx] = v;
}

// ---------------- main kernel
// FOLDED=true : w points at wf[c][i][o] (scale baked in)
// FOLDED=false: w points at raw weights[o][i][5] (scale applied at epilogue)
template <bool FOLDED>
__global__ __launch_bounds__(128) void sph_kernel(const float* __restrict__ x,
                                                  const float* __restrict__ w,
                                                  const int* __restrict__ ls,
                                                  float* __restrict__ out) {
    __shared__ float xs[CG * C_STRIDE];   // 8480 floats = 33.9 KB

    const int bid = blockIdx.x;           // 768 blocks
    // XCD swizzle: all 6 c-groups of a b-tile land on the same XCD (L2 line sharing)
    const int xcd  = bid & 7;
    const int slot = bid >> 3;            // [0, 96)
    const int q    = slot / NCG;          // [0, 16)
    const int cg   = slot - q * NCG;      // [0, 6)
    const int bt   = xcd * 16 + q;        // [0, 128)
    const int cb   = cg * CG;
    const int tid  = threadIdx.x;

    // ---- stage x[bt*16 .. +16)[*][cb .. cb+8) into LDS (transposed) ----
    const size_t xbase0 = (size_t)bt * (BT * IC * NSH);
#pragma unroll
    for (int k = 0; k < 16; ++k) {
        int s  = k * 128 + tid;           // [0, 2048) float4-slots
        int ch = s & 1;                   // which half of the 8 c's
        int bb = (s >> 1) & 15;           // batch row in tile
        int ii = s >> 5;                  // [0, 64) input channel
        int c0 = ch * 4;
        size_t g = xbase0 + (size_t)bb * (IC * NSH) + (size_t)ii * NSH + cb + c0;
        f4u v;
        if (g + 3 < XTOT) {
            v = *(const f4u*)(x + g);     // 4B-aligned vector load
        } else {
            v.x = (g + 0 < XTOT) ? x[g + 0] : 0.0f;
            v.y = (g + 1 < XTOT) ? x[g + 1] : 0.0f;
            v.z = (g + 2 < XTOT) ? x[g + 2] : 0.0f;
            v.w = (g + 3 < XTOT) ? x[g + 3] : 0.0f;
        }
        int bg   = bb >> 3;
        int bl   = bb & 7;
        int base = bg * BG_STRIDE + ii * 8 + bl;
        xs[(c0 + 0) * C_STRIDE + base] = v.x;
        xs[(c0 + 1) * C_STRIDE + base] = v.y;
        xs[(c0 + 2) * C_STRIDE + base] = v.z;
        xs[(c0 + 3) * C_STRIDE + base] = v.w;
    }
    __syncthreads();

    // ---- compute: thread = (bg, og, ci); 8x8 register tile, one c ----
    const int bg = tid & 1;
    const int og = (tid >> 1) & 7;
    const int ci = tid >> 4;              // [0, 8)
    const int c  = cb + ci;               // may be >= 45 in last c-group
    const int o0 = og * 8;

    float acc[8][8];
#pragma unroll
    for (int a = 0; a < 8; ++a)
#pragma unroll
        for (int b = 0; b < 8; ++b) acc[a][b] = 0.0f;

    const float* xp = xs + ci * C_STRIDE + bg * BG_STRIDE;

    if (FOLDED) {
        const float* wp = w + ((size_t)c * IC) * OC + o0;   // wf[c][i][o0], i-stride 64
#pragma unroll 4
        for (int i = 0; i < IC; ++i) {
            float4 xa = *(const float4*)(xp + i * 8);
            float4 xb = *(const float4*)(xp + i * 8 + 4);
            float4 wa = *(const float4*)(wp + i * OC);
            float4 wb = *(const float4*)(wp + i * OC + 4);
            float xv[8] = {xa.x, xa.y, xa.z, xa.w, xb.x, xb.y, xb.z, xb.w};
            float wv[8] = {wa.x, wa.y, wa.z, wa.w, wb.x, wb.y, wb.z, wb.w};
#pragma unroll
            for (int a = 0; a < 8; ++a)
#pragma unroll
                for (int b = 0; b < 8; ++b)
                    acc[a][b] = fmaf(xv[a], wv[b], acc[a][b]);
        }
    } else {
        int l2c = ls[c < NSH ? c : NSH - 1] >> 1;
        const float* wp = w + (size_t)o0 * (IC * 5) + l2c;  // weights[o][i][l2], o-stride 320, i-stride 5
#pragma unroll 2
        for (int i = 0; i < IC; ++i) {
            float4 xa = *(const float4*)(xp + i * 8);
            float4 xb = *(const float4*)(xp + i * 8 + 4);
            float xv[8] = {xa.x, xa.y, xa.z, xa.w, xb.x, xb.y, xb.z, xb.w};
            float wv[8];
#pragma unroll
            for (int u = 0; u < 8; ++u) wv[u] = wp[(size_t)u * (IC * 5) + i * 5];
#pragma unroll
            for (int a = 0; a < 8; ++a)
#pragma unroll
                for (int b = 0; b < 8; ++b)
                    acc[a][b] = fmaf(xv[a], wv[b], acc[a][b]);
        }
    }

    // ---- epilogue ----
    if (c < NSH) {
        float sc = 1.0f;
        if (!FOLDED) {
            int l = ls[c];
            sc = sqrtf(PI_F / (2.0f * (float)l + 1.0f));
        }
        size_t orow = ((size_t)(bt * BT + bg * 8) * OC + o0) * NSH + c;
#pragma unroll
        for (int a = 0; a < 8; ++a) {
#pragma unroll
            for (int b = 0; b < 8; ++b) {
                float r = FOLDED ? acc[a][b] : acc[a][b] * sc;
                out[orow + (size_t)a * (OC * NSH) + (size_t)b * NSH] = r;
            }
        }
    }
}

extern "C" void kernel_launch(void* const* d_in, const int* in_sizes, int n_in,
                              void* d_out, int out_size, void* d_ws, size_t ws_size,
                              hipStream_t stream) {
    const float* x  = (const float*)d_in[0];
    const float* wt = (const float*)d_in[1];
    const int*   ls = (const int*)d_in[2];
    float* out = (float*)d_out;

    const int nblocks = NBT * NCG;  // 768

    if (ws_size >= (size_t)WF_ELEMS * sizeof(float)) {
        float* wf = (float*)d_ws;
        fold_kernel<<<WF_ELEMS / 256, 256, 0, stream>>>(wt, ls, wf);
        sph_kernel<true><<<nblocks, 128, 0, stream>>>(x, wf, ls, out);
    } else {
        sph_kernel<false><<<nblocks, 128, 0, stream>>>(x, wt, ls, out);
    }
}